// Round 2
// baseline (363.378 us; speedup 1.0000x reference)
//
#include <hip/hip_runtime.h>
#include <math.h>

#define BN_EPS 1e-5
#define SIGMA 1.0f

// ---------------- conv1: (8,128,64,64) -> (8,64,32,32), 3x3 s2 p1, BN+ReLU, fp64 accum ----------------
__global__ __launch_bounds__(256) void conv1_kernel(
    const float* __restrict__ in, const float* __restrict__ w,
    const float* __restrict__ g, const float* __restrict__ be,
    const float* __restrict__ mn, const float* __restrict__ vr,
    double* __restrict__ out)
{
    __shared__ double wsm[128 * 9];
    int idx = blockIdx.x * 256 + threadIdx.x;
    int ow = idx & 31;
    int oh = (idx >> 5) & 31;
    int oc = (idx >> 10) & 63;   // uniform within block (256 threads span ow + low bits of oh)
    int b  = idx >> 16;

    for (int i = threadIdx.x; i < 128 * 9; i += 256) wsm[i] = (double)w[oc * 128 * 9 + i];
    __syncthreads();

    const float* inb = in + (size_t)b * 128 * 4096;
    double acc = 0.0;
    int ih0 = 2 * oh - 1;
    int iw0 = 2 * ow - 1;
    for (int ic = 0; ic < 128; ++ic) {
        const float* inc = inb + ic * 4096;
        const double* wp = wsm + ic * 9;
        #pragma unroll
        for (int kh = 0; kh < 3; ++kh) {
            int ih = ih0 + kh;
            if ((unsigned)ih < 64u) {
                const float* row = inc + ih * 64;
                #pragma unroll
                for (int kw = 0; kw < 3; ++kw) {
                    int iw = iw0 + kw;
                    double v = ((unsigned)iw < 64u) ? (double)row[iw] : 0.0;
                    acc = fma(v, wp[kh * 3 + kw], acc);
                }
            }
        }
    }
    double inv = (double)g[oc] / sqrt((double)vr[oc] + BN_EPS);
    double o = acc * inv + ((double)be[oc] - (double)mn[oc] * inv);
    out[idx] = fmax(o, 0.0);
}

// ---------------- conv2: (8,64,32,32) -> (8,32,16,16), 3x3 s2 p1, BN+ReLU, fp64 ----------------
__global__ __launch_bounds__(256) void conv2_kernel(
    const double* __restrict__ in, const float* __restrict__ w,
    const float* __restrict__ g, const float* __restrict__ be,
    const float* __restrict__ mn, const float* __restrict__ vr,
    double* __restrict__ out)
{
    __shared__ double wsm[64 * 9];
    int idx = blockIdx.x * 256 + threadIdx.x;
    int ow = idx & 15;
    int oh = (idx >> 4) & 15;
    int oc = (idx >> 8) & 31;    // uniform within block
    int b  = idx >> 13;

    for (int i = threadIdx.x; i < 64 * 9; i += 256) wsm[i] = (double)w[oc * 64 * 9 + i];
    __syncthreads();

    const double* inb = in + (size_t)b * 64 * 1024;
    double acc = 0.0;
    int ih0 = 2 * oh - 1;
    int iw0 = 2 * ow - 1;
    for (int ic = 0; ic < 64; ++ic) {
        const double* inc = inb + ic * 1024;
        const double* wp  = wsm + ic * 9;
        #pragma unroll
        for (int kh = 0; kh < 3; ++kh) {
            int ih = ih0 + kh;
            if ((unsigned)ih < 32u) {
                const double* row = inc + ih * 32;
                #pragma unroll
                for (int kw = 0; kw < 3; ++kw) {
                    int iw = iw0 + kw;
                    double v = ((unsigned)iw < 32u) ? row[iw] : 0.0;
                    acc = fma(v, wp[kh * 3 + kw], acc);
                }
            }
        }
    }
    double inv = (double)g[oc] / sqrt((double)vr[oc] + BN_EPS);
    double o = acc * inv + ((double)be[oc] - (double)mn[oc] * inv);
    out[idx] = fmax(o, 0.0);
}

// ---------------- per-(b,ic) spatial mean of conv2 output: 256 blocks -> ybar[256], fp64 ----------------
__global__ __launch_bounds__(256) void ybar_kernel(const double* __restrict__ y, double* __restrict__ ybar)
{
    __shared__ double s[4];
    int j = blockIdx.x;                 // j = b*32 + ic
    double v = y[j * 256 + threadIdx.x];
    #pragma unroll
    for (int o = 32; o > 0; o >>= 1) v += __shfl_down(v, o, 64);
    if ((threadIdx.x & 63) == 0) s[threadIdx.x >> 6] = v;
    __syncthreads();
    if (threadIdx.x == 0) ybar[j] = (s[0] + s[1] + s[2] + s[3]) * (1.0 / 256.0);
}

// ---------------- centers: conv3(1x1)+BN folded with the spatial mean, fp64 ----------------
__global__ __launch_bounds__(64) void centers_kernel(
    const double* __restrict__ ybar, const float* __restrict__ w3,
    const float* __restrict__ g, const float* __restrict__ be,
    const float* __restrict__ mn, const float* __restrict__ vr,
    double* __restrict__ cen_ws, float* __restrict__ cen_out)
{
    int t = threadIdx.x;
    if (t < 48) {
        int b = t / 6;
        int k = t % 6;
        double acc = 0.0;
        for (int ic = 0; ic < 32; ++ic) acc = fma((double)w3[k * 32 + ic], ybar[b * 32 + ic], acc);
        double inv = (double)g[k] / sqrt((double)vr[k] + BN_EPS);
        double c = acc * inv + ((double)be[k] - (double)mn[k] * inv);
        cen_ws[t]  = c;
        cen_out[t] = (float)c;
    }
}

// ---------------- quantization: fp64 dist/argmin, fp32 softmax; float4-vectorized I/O ----------------
__global__ __launch_bounds__(256) void quant_kernel(
    const float* __restrict__ x, const double* __restrict__ centers,
    float* __restrict__ qbar, float* __restrict__ qsoft,
    float* __restrict__ qhard, float* __restrict__ sym)
{
    int vid = blockIdx.x * 256 + threadIdx.x;   // float4 index; 2^17 vecs per batch
    int b = vid >> 17;                          // 128*64*64/4 = 131072 = 2^17

    double c[6];
    float cf[6];
    #pragma unroll
    for (int k = 0; k < 6; ++k) { c[k] = centers[b * 6 + k]; cf[k] = (float)c[k]; }

    float4 xv = ((const float4*)x)[vid];
    float xs[4] = {xv.x, xv.y, xv.z, xv.w};
    float r_bar[4], r_soft[4], r_hard[4], r_sym[4];

    #pragma unroll
    for (int i = 0; i < 4; ++i) {
        double xx = (double)xs[i];
        double d[6];
        double dmin = 1e300;
        int amin = 0;
        #pragma unroll
        for (int k = 0; k < 6; ++k) {
            double t = xx - c[k];
            d[k] = t * t;
            if (d[k] < dmin) { dmin = d[k]; amin = k; }   // strict < keeps first occurrence
        }
        float se = 0.f, sw = 0.f;
        #pragma unroll
        for (int k = 0; k < 6; ++k) {
            float e = __expf(SIGMA * (float)(dmin - d[k]));  // softmax(-sigma*d) after max-shift
            se += e;
            sw += e * cf[k];
        }
        float qs = sw / se;
        float qh = cf[amin];
        r_soft[i] = qs;
        r_hard[i] = qh;
        r_bar[i]  = qh;                 // qsoft + (qhard - qsoft) == qhard in value
        r_sym[i]  = (float)amin;
    }

    ((float4*)qbar)[vid]  = make_float4(r_bar[0],  r_bar[1],  r_bar[2],  r_bar[3]);
    ((float4*)qsoft)[vid] = make_float4(r_soft[0], r_soft[1], r_soft[2], r_soft[3]);
    ((float4*)qhard)[vid] = make_float4(r_hard[0], r_hard[1], r_hard[2], r_hard[3]);
    ((float4*)sym)[vid]   = make_float4(r_sym[0],  r_sym[1],  r_sym[2],  r_sym[3]);
}

extern "C" void kernel_launch(void* const* d_in, const int* in_sizes, int n_in,
                              void* d_out, int out_size, void* d_ws, size_t ws_size,
                              hipStream_t stream) {
    const float* x  = (const float*)d_in[0];
    const float* cf = (const float*)d_in[1];
    const float* w1 = (const float*)d_in[2];
    const float* g1 = (const float*)d_in[3];
    const float* b1 = (const float*)d_in[4];
    const float* m1 = (const float*)d_in[5];
    const float* v1 = (const float*)d_in[6];
    const float* w2 = (const float*)d_in[7];
    const float* g2 = (const float*)d_in[8];
    const float* b2 = (const float*)d_in[9];
    const float* m2 = (const float*)d_in[10];
    const float* v2 = (const float*)d_in[11];
    const float* w3 = (const float*)d_in[12];
    const float* g3 = (const float*)d_in[13];
    const float* b3 = (const float*)d_in[14];
    const float* m3 = (const float*)d_in[15];
    const float* v3 = (const float*)d_in[16];

    const int NELEM = 8 * 128 * 64 * 64;      // 4,194,304 = 2^22
    float* out   = (float*)d_out;
    float* qbar  = out;
    float* qsoft = out + (size_t)NELEM;
    float* qhard = out + (size_t)2 * NELEM;
    float* sym   = out + (size_t)3 * NELEM;
    float* cen_o = out + (size_t)4 * NELEM;   // 48 floats

    double* ws  = (double*)d_ws;
    double* c1  = ws;                   // 8*64*32*32 = 524288 doubles (4 MB)
    double* c2  = ws + 524288;          // 8*32*16*16 = 65536 doubles (512 KB)
    double* yb  = ws + 524288 + 65536;  // 256 doubles
    double* cen = yb + 256;             // 48 doubles

    conv1_kernel<<<2048, 256, 0, stream>>>(cf, w1, g1, b1, m1, v1, c1);
    conv2_kernel<<<256, 256, 0, stream>>>(c1, w2, g2, b2, m2, v2, c2);
    ybar_kernel<<<256, 256, 0, stream>>>(c2, yb);
    centers_kernel<<<1, 64, 0, stream>>>(yb, w3, g3, b3, m3, v3, cen, cen_o);
    quant_kernel<<<NELEM / 4 / 256, 256, 0, stream>>>(x, cen, qbar, qsoft, qhard, sym);  // 4096 blocks
}

// Round 4
// 238.373 us; speedup vs baseline: 1.5244x; 1.5244x over previous
//
#include <hip/hip_runtime.h>
#include <math.h>

#define BN_EPS 1e-5
#define SIGMA 1.0f

// ============ conv1 partial: (8,128,64,64) -> fp32 partial sums, 3x3 s2 p1 ============
// grid 1024 = icsplit(4) x b(8) x ohtile(4) x ocg(8); block 256 = ow(32) x ohl(8)
// each thread: 8 oc accumulators (fp64), over 32 ic in 4 chunks of 8
__global__ __launch_bounds__(256) void conv1_partial_kernel(
    const float* __restrict__ in, const float* __restrict__ w,
    float* __restrict__ part)
{
    __shared__ float tin[8][17][68];   // [ic][row(-1..15 local)][col+1 (0..65)]
    __shared__ float twt[8][9][8];     // [ic][k][oc]

    int bid = blockIdx.x;
    int ocg = bid & 7;
    int oht = (bid >> 3) & 3;
    int b   = (bid >> 5) & 7;
    int isp = bid >> 8;            // 0..3

    int tid = threadIdx.x;
    int ow  = tid & 31;
    int ohl = tid >> 5;            // 0..7
    int oh  = oht * 8 + ohl;

    double acc[8];
    #pragma unroll
    for (int j = 0; j < 8; ++j) acc[j] = 0.0;

    const float* inb = in + (size_t)(b * 128 + isp * 32) * 4096;

    for (int ch = 0; ch < 4; ++ch) {
        int ic0 = ch * 8;          // within this split's 32 ic
        __syncthreads();
        // ---- stage input: 8 ic x 17 rows x 66 cols, zero-padded ----
        for (int lin = tid; lin < 8 * 17 * 66; lin += 256) {
            int c   = lin % 66;            // iw = c-1
            int t2  = lin / 66;
            int rr  = t2 % 17;             // ih = 16*oht - 1 + rr
            int icc = t2 / 17;
            int ih  = 16 * oht - 1 + rr;
            int iw  = c - 1;
            float v = 0.f;
            if ((unsigned)ih < 64u && (unsigned)iw < 64u)
                v = inb[((ic0 + icc) * 64 + ih) * 64 + iw];
            tin[icc][rr][c] = v;
        }
        // ---- stage weights: twt[icc][k][j] = w[(ocg*8+j)][isp*32+ic0+icc][k] ----
        for (int i = tid; i < 576; i += 256) {     // FIX: was `if (tid < 576)` with 256 threads
            int j   = i & 7;
            int k   = (i >> 3) % 9;
            int icc = i / 72;
            twt[icc][k][j] = w[(ocg * 8 + j) * 1152 + (isp * 32 + ic0 + icc) * 9 + k];
        }
        __syncthreads();
        // ---- compute ----
        for (int icc = 0; icc < 8; ++icc) {
            double xv[9];
            #pragma unroll
            for (int kh = 0; kh < 3; ++kh)
                #pragma unroll
                for (int kw = 0; kw < 3; ++kw)
                    xv[kh * 3 + kw] = (double)tin[icc][2 * ohl + kh][2 * ow + kw];
            #pragma unroll
            for (int k = 0; k < 9; ++k) {
                float4 wa = *(const float4*)&twt[icc][k][0];
                float4 wb = *(const float4*)&twt[icc][k][4];
                acc[0] = fma(xv[k], (double)wa.x, acc[0]);
                acc[1] = fma(xv[k], (double)wa.y, acc[1]);
                acc[2] = fma(xv[k], (double)wa.z, acc[2]);
                acc[3] = fma(xv[k], (double)wa.w, acc[3]);
                acc[4] = fma(xv[k], (double)wb.x, acc[4]);
                acc[5] = fma(xv[k], (double)wb.y, acc[5]);
                acc[6] = fma(xv[k], (double)wb.z, acc[6]);
                acc[7] = fma(xv[k], (double)wb.w, acc[7]);
            }
        }
    }
    int obase = ((b * 64 + ocg * 8) * 32 + oh) * 32 + ow;
    #pragma unroll
    for (int j = 0; j < 8; ++j)
        part[isp * 524288 + obase + j * 1024] = (float)acc[j];
}

// ============ conv1 combine: sum 4 partials + BN + ReLU -> y1 fp32 ============
__global__ __launch_bounds__(256) void conv1_combine_kernel(
    const float* __restrict__ part,
    const float* __restrict__ g, const float* __restrict__ be,
    const float* __restrict__ mn, const float* __restrict__ vr,
    float* __restrict__ y1)
{
    int idx = blockIdx.x * 256 + threadIdx.x;   // [b][oc][oh][ow], 524288 total
    int oc = (idx >> 10) & 63;
    double s = (double)part[idx] + (double)part[idx + 524288]
             + (double)part[idx + 2 * 524288] + (double)part[idx + 3 * 524288];
    double inv = (double)g[oc] / sqrt((double)vr[oc] + BN_EPS);
    double o = s * inv + ((double)be[oc] - (double)mn[oc] * inv);
    y1[idx] = fmaxf((float)o, 0.f);
}

// ============ conv2 partial: (8,64,32,32) -> fp32 partials, 3x3 s2 p1 ============
// grid 512 = icsplit(16) x b(8) x ocg(4); block 256 = full 16x16 spatial; 4 ic per block
__global__ __launch_bounds__(256) void conv2_partial_kernel(
    const float* __restrict__ y1, const float* __restrict__ w,
    float* __restrict__ part)
{
    __shared__ float tin[4][33][36];   // [ic][row+1 (0..32)][col+1 (0..33)]
    __shared__ float twt[4][9][8];

    int bid = blockIdx.x;
    int ocg = bid & 3;
    int b   = (bid >> 2) & 7;
    int isp = bid >> 5;            // 0..15, 4 ic each

    int tid = threadIdx.x;
    int ow  = tid & 15;
    int oh  = tid >> 4;

    const float* inb = y1 + (size_t)(b * 64 + isp * 4) * 1024;

    // ---- stage input: 4 ic x 33 rows x 34 cols, zero-padded ----
    for (int lin = tid; lin < 4 * 33 * 34; lin += 256) {
        int c   = lin % 34;            // iw = c-1
        int t2  = lin / 34;
        int rr  = t2 % 33;             // ih = rr-1
        int icc = t2 / 33;
        int ih  = rr - 1;
        int iw  = c - 1;
        float v = 0.f;
        if ((unsigned)ih < 32u && (unsigned)iw < 32u)
            v = inb[(icc * 32 + ih) * 32 + iw];
        tin[icc][rr][c] = v;
    }
    for (int i = tid; i < 288; i += 256) {     // FIX: was `if (tid < 288)` with 256 threads
        int j   = i & 7;
        int k   = (i >> 3) % 9;
        int icc = i / 72;
        twt[icc][k][j] = w[(ocg * 8 + j) * 576 + (isp * 4 + icc) * 9 + k];
    }
    __syncthreads();

    double acc[8];
    #pragma unroll
    for (int j = 0; j < 8; ++j) acc[j] = 0.0;

    for (int icc = 0; icc < 4; ++icc) {
        double xv[9];
        #pragma unroll
        for (int kh = 0; kh < 3; ++kh)
            #pragma unroll
            for (int kw = 0; kw < 3; ++kw)
                xv[kh * 3 + kw] = (double)tin[icc][2 * oh + kh][2 * ow + kw];
        #pragma unroll
        for (int k = 0; k < 9; ++k) {
            float4 wa = *(const float4*)&twt[icc][k][0];
            float4 wb = *(const float4*)&twt[icc][k][4];
            acc[0] = fma(xv[k], (double)wa.x, acc[0]);
            acc[1] = fma(xv[k], (double)wa.y, acc[1]);
            acc[2] = fma(xv[k], (double)wa.z, acc[2]);
            acc[3] = fma(xv[k], (double)wa.w, acc[3]);
            acc[4] = fma(xv[k], (double)wb.x, acc[4]);
            acc[5] = fma(xv[k], (double)wb.y, acc[5]);
            acc[6] = fma(xv[k], (double)wb.z, acc[6]);
            acc[7] = fma(xv[k], (double)wb.w, acc[7]);
        }
    }
    int obase = ((b * 32 + ocg * 8) * 16 + oh) * 16 + ow;
    #pragma unroll
    for (int j = 0; j < 8; ++j)
        part[isp * 65536 + obase + j * 256] = (float)acc[j];
}

// ============ conv2 combine: sum 16 partials + BN + ReLU -> y2 fp32 ============
__global__ __launch_bounds__(256) void conv2_combine_kernel(
    const float* __restrict__ part,
    const float* __restrict__ g, const float* __restrict__ be,
    const float* __restrict__ mn, const float* __restrict__ vr,
    float* __restrict__ y2)
{
    int idx = blockIdx.x * 256 + threadIdx.x;   // [b][oc][oh][ow], 65536 total
    int oc = (idx >> 8) & 31;
    double s = 0.0;
    #pragma unroll
    for (int p = 0; p < 16; ++p) s += (double)part[idx + p * 65536];
    double inv = (double)g[oc] / sqrt((double)vr[oc] + BN_EPS);
    double o = s * inv + ((double)be[oc] - (double)mn[oc] * inv);
    y2[idx] = fmaxf((float)o, 0.f);
}

// ============ per-(b,ic) spatial mean: 256 blocks -> ybar[256] fp64 ============
__global__ __launch_bounds__(256) void ybar_kernel(const float* __restrict__ y, double* __restrict__ ybar)
{
    __shared__ double s[4];
    int j = blockIdx.x;                 // j = b*32 + ic
    double v = (double)y[j * 256 + threadIdx.x];
    #pragma unroll
    for (int o = 32; o > 0; o >>= 1) v += __shfl_down(v, o, 64);
    if ((threadIdx.x & 63) == 0) s[threadIdx.x >> 6] = v;
    __syncthreads();
    if (threadIdx.x == 0) ybar[j] = (s[0] + s[1] + s[2] + s[3]) * (1.0 / 256.0);
}

// ============ centers: conv3(1x1)+BN folded with the spatial mean, fp64 ============
__global__ __launch_bounds__(64) void centers_kernel(
    const double* __restrict__ ybar, const float* __restrict__ w3,
    const float* __restrict__ g, const float* __restrict__ be,
    const float* __restrict__ mn, const float* __restrict__ vr,
    double* __restrict__ cen_ws, float* __restrict__ cen_out)
{
    int t = threadIdx.x;
    if (t < 48) {
        int b = t / 6;
        int k = t % 6;
        double acc = 0.0;
        for (int ic = 0; ic < 32; ++ic) acc = fma((double)w3[k * 32 + ic], ybar[b * 32 + ic], acc);
        double inv = (double)g[k] / sqrt((double)vr[k] + BN_EPS);
        double c = acc * inv + ((double)be[k] - (double)mn[k] * inv);
        cen_ws[t]  = c;
        cen_out[t] = (float)c;
    }
}

// ============ quantization: fp64 dist/argmin, fp32 softmax; float4 I/O ============
__global__ __launch_bounds__(256) void quant_kernel(
    const float* __restrict__ x, const double* __restrict__ centers,
    float* __restrict__ qbar, float* __restrict__ qsoft,
    float* __restrict__ qhard, float* __restrict__ sym)
{
    int vid = blockIdx.x * 256 + threadIdx.x;   // float4 index; 2^17 vecs per batch
    int b = vid >> 17;

    double c[6];
    float cf[6];
    #pragma unroll
    for (int k = 0; k < 6; ++k) { c[k] = centers[b * 6 + k]; cf[k] = (float)c[k]; }

    float4 xv = ((const float4*)x)[vid];
    float xs[4] = {xv.x, xv.y, xv.z, xv.w};
    float r_bar[4], r_soft[4], r_hard[4], r_sym[4];

    #pragma unroll
    for (int i = 0; i < 4; ++i) {
        double xx = (double)xs[i];
        double d[6];
        double dmin = 1e300;
        int amin = 0;
        #pragma unroll
        for (int k = 0; k < 6; ++k) {
            double t = xx - c[k];
            d[k] = t * t;
            if (d[k] < dmin) { dmin = d[k]; amin = k; }
        }
        float se = 0.f, sw = 0.f;
        #pragma unroll
        for (int k = 0; k < 6; ++k) {
            float e = __expf(SIGMA * (float)(dmin - d[k]));
            se += e;
            sw += e * cf[k];
        }
        float qs = sw / se;
        float qh = cf[amin];
        r_soft[i] = qs;
        r_hard[i] = qh;
        r_bar[i]  = qh;
        r_sym[i]  = (float)amin;
    }

    ((float4*)qbar)[vid]  = make_float4(r_bar[0],  r_bar[1],  r_bar[2],  r_bar[3]);
    ((float4*)qsoft)[vid] = make_float4(r_soft[0], r_soft[1], r_soft[2], r_soft[3]);
    ((float4*)qhard)[vid] = make_float4(r_hard[0], r_hard[1], r_hard[2], r_hard[3]);
    ((float4*)sym)[vid]   = make_float4(r_sym[0],  r_sym[1],  r_sym[2],  r_sym[3]);
}

extern "C" void kernel_launch(void* const* d_in, const int* in_sizes, int n_in,
                              void* d_out, int out_size, void* d_ws, size_t ws_size,
                              hipStream_t stream) {
    const float* x  = (const float*)d_in[0];
    const float* cf = (const float*)d_in[1];
    const float* w1 = (const float*)d_in[2];
    const float* g1 = (const float*)d_in[3];
    const float* b1 = (const float*)d_in[4];
    const float* m1 = (const float*)d_in[5];
    const float* v1 = (const float*)d_in[6];
    const float* w2 = (const float*)d_in[7];
    const float* g2 = (const float*)d_in[8];
    const float* b2 = (const float*)d_in[9];
    const float* m2 = (const float*)d_in[10];
    const float* v2 = (const float*)d_in[11];
    const float* w3 = (const float*)d_in[12];
    const float* g3 = (const float*)d_in[13];
    const float* b3 = (const float*)d_in[14];
    const float* m3 = (const float*)d_in[15];
    const float* v3 = (const float*)d_in[16];

    const int NELEM = 8 * 128 * 64 * 64;      // 4,194,304
    float* out   = (float*)d_out;
    float* qbar  = out;
    float* qsoft = out + (size_t)NELEM;
    float* qhard = out + (size_t)2 * NELEM;
    float* sym   = out + (size_t)3 * NELEM;
    float* cen_o = out + (size_t)4 * NELEM;   // 48 floats

    char* ws = (char*)d_ws;
    float*  part1 = (float*)(ws);                        // 4 x 524288 f32 = 8 MB
    float*  y1    = (float*)(ws + 8388608);              // 524288 f32 = 2 MB
    float*  part2 = (float*)(ws + 10485760);             // 16 x 65536 f32 = 4 MB
    float*  y2    = (float*)(ws + 14680064);             // 65536 f32
    double* yb    = (double*)(ws + 14942208);            // 256 f64
    double* cen   = (double*)(ws + 14944256);            // 48 f64

    conv1_partial_kernel<<<1024, 256, 0, stream>>>(cf, w1, part1);
    conv1_combine_kernel<<<2048, 256, 0, stream>>>(part1, g1, b1, m1, v1, y1);
    conv2_partial_kernel<<<512, 256, 0, stream>>>(y1, w2, part2);
    conv2_combine_kernel<<<256, 256, 0, stream>>>(part2, g2, b2, m2, v2, y2);
    ybar_kernel<<<256, 256, 0, stream>>>(y2, yb);
    centers_kernel<<<1, 64, 0, stream>>>(yb, w3, g3, b3, m3, v3, cen, cen_o);
    quant_kernel<<<NELEM / 4 / 256, 256, 0, stream>>>(x, cen, qbar, qsoft, qhard, sym);
}

// Round 5
// 191.272 us; speedup vs baseline: 1.8998x; 1.2463x over previous
//
#include <hip/hip_runtime.h>
#include <math.h>

#define BN_EPS 1e-5
#define SIGMA 1.0f

// ============ weight pre-convert: w1 fp32 -> w1d fp64, layout [ocg][ic][k][j] ============
// i = ((ocg*128 + ic)*9 + k)*8 + j ;  src = ((ocg*8 + j)*128 + ic)*9 + k
__global__ __launch_bounds__(256) void wcvt_kernel(const float* __restrict__ w1, double* __restrict__ w1d)
{
    int i = blockIdx.x * 256 + threadIdx.x;   // 73728 total
    if (i < 73728) {
        int j   = i & 7;
        int t   = i >> 3;
        int k   = t % 9;
        int t2  = t / 9;
        int ic  = t2 & 127;
        int ocg = t2 >> 7;
        w1d[i] = (double)w1[((ocg * 8 + j) * 128 + ic) * 9 + k];
    }
}

// ============ conv1 partial: direct-load, fp64 acc, 2 rows x 8 oc per thread ============
// grid 512: tile = bid & 63 (isp2 x b8 x oht... isp = tile>>4 (0..3), b = (tile>>1)&7, oht = tile&1)
//           ocg = bid >> 6 (high bits -> all 8 input-sharing siblings on same XCD)
// block 256 = ow(32) x ohp(8); thread covers output rows oh0, oh0+1 (oh0 = oht*16 + ohp*2)
__global__ __launch_bounds__(256) void conv1_partial_kernel(
    const float* __restrict__ in, const double* __restrict__ w1d,
    float* __restrict__ part)
{
    __shared__ double wlds[2304];   // [ic_local(32)][k(9)][j(8)] = 18.4 KB

    int bid  = blockIdx.x;
    int tile = bid & 63;
    int ocg  = bid >> 6;
    int isp  = tile >> 4;          // 0..3  (32 ic each)
    int b    = (tile >> 1) & 7;
    int oht  = tile & 1;           // 16-row half

    int tid = threadIdx.x;
    int ow  = tid & 31;
    int ohp = tid >> 5;            // 0..7
    int oh0 = oht * 16 + ohp * 2;
    int ih0 = 2 * oh0 - 1;
    int iw0 = 2 * ow - 1;

    // ---- stage this block's weights (contiguous fp64 chunk) ----
    const double* wsrc = w1d + (size_t)(ocg * 128 + isp * 32) * 72;
    for (int i = tid; i < 2304; i += 256) wlds[i] = wsrc[i];
    __syncthreads();

    double acc0[8], acc1[8];
    #pragma unroll
    for (int j = 0; j < 8; ++j) { acc0[j] = 0.0; acc1[j] = 0.0; }

    // predicates (only -1 edges can be invalid; max indices are always <= 63)
    bool rowok[5], colok[3];
    #pragma unroll
    for (int t = 0; t < 5; ++t) rowok[t] = (ih0 + t) >= 0;
    #pragma unroll
    for (int kw = 0; kw < 3; ++kw) colok[kw] = (iw0 + kw) >= 0;

    const float* base0 = in + ((size_t)(b * 128 + isp * 32) * 64 + ih0) * 64 + iw0;

    float cur[15];
    #pragma unroll
    for (int t = 0; t < 5; ++t)
        #pragma unroll
        for (int kw = 0; kw < 3; ++kw)
            cur[t * 3 + kw] = (rowok[t] && colok[kw]) ? base0[t * 64 + kw] : 0.f;

    #pragma unroll 2
    for (int ic = 0; ic < 32; ++ic) {
        // prefetch next ic's 15 taps
        float nxt[15];
        if (ic + 1 < 32) {
            const float* basen = base0 + (size_t)(ic + 1) * 4096;
            #pragma unroll
            for (int t = 0; t < 5; ++t)
                #pragma unroll
                for (int kw = 0; kw < 3; ++kw)
                    nxt[t * 3 + kw] = (rowok[t] && colok[kw]) ? basen[t * 64 + kw] : 0.f;
        }
        // convert current taps once
        double xv[15];
        #pragma unroll
        for (int i = 0; i < 15; ++i) xv[i] = (double)cur[i];

        const double* wk = &wlds[ic * 72];
        #pragma unroll
        for (int k = 0; k < 9; ++k) {
            int kh = k / 3, kw = k % 3;
            double2 wa = *(const double2*)&wk[k * 8 + 0];
            double2 wb = *(const double2*)&wk[k * 8 + 2];
            double2 wc = *(const double2*)&wk[k * 8 + 4];
            double2 wd = *(const double2*)&wk[k * 8 + 6];
            double x0 = xv[kh * 3 + kw];        // output row oh0   (t = kh)
            double x1 = xv[(kh + 2) * 3 + kw];  // output row oh0+1 (t = kh+2)
            acc0[0] = fma(x0, wa.x, acc0[0]);  acc1[0] = fma(x1, wa.x, acc1[0]);
            acc0[1] = fma(x0, wa.y, acc0[1]);  acc1[1] = fma(x1, wa.y, acc1[1]);
            acc0[2] = fma(x0, wb.x, acc0[2]);  acc1[2] = fma(x1, wb.x, acc1[2]);
            acc0[3] = fma(x0, wb.y, acc0[3]);  acc1[3] = fma(x1, wb.y, acc1[3]);
            acc0[4] = fma(x0, wc.x, acc0[4]);  acc1[4] = fma(x1, wc.x, acc1[4]);
            acc0[5] = fma(x0, wc.y, acc0[5]);  acc1[5] = fma(x1, wc.y, acc1[5]);
            acc0[6] = fma(x0, wd.x, acc0[6]);  acc1[6] = fma(x1, wd.x, acc1[6]);
            acc0[7] = fma(x0, wd.y, acc0[7]);  acc1[7] = fma(x1, wd.y, acc1[7]);
        }
        #pragma unroll
        for (int i = 0; i < 15; ++i) cur[i] = nxt[i];
    }

    #pragma unroll
    for (int j = 0; j < 8; ++j) {
        int idx0 = ((b * 64 + ocg * 8 + j) * 32 + oh0) * 32 + ow;
        part[isp * 524288 + idx0]      = (float)acc0[j];
        part[isp * 524288 + idx0 + 32] = (float)acc1[j];   // row oh0+1
    }
}

// ============ conv1 combine: sum 4 partials + BN + ReLU -> y1 fp32 ============
__global__ __launch_bounds__(256) void conv1_combine_kernel(
    const float* __restrict__ part,
    const float* __restrict__ g, const float* __restrict__ be,
    const float* __restrict__ mn, const float* __restrict__ vr,
    float* __restrict__ y1)
{
    int idx = blockIdx.x * 256 + threadIdx.x;   // [b][oc][oh][ow], 524288 total
    int oc = (idx >> 10) & 63;
    double s = (double)part[idx] + (double)part[idx + 524288]
             + (double)part[idx + 2 * 524288] + (double)part[idx + 3 * 524288];
    double inv = (double)g[oc] / sqrt((double)vr[oc] + BN_EPS);
    double o = s * inv + ((double)be[oc] - (double)mn[oc] * inv);
    y1[idx] = fmaxf((float)o, 0.f);
}

// ============ conv2 partial: (8,64,32,32) -> fp32 partials, 3x3 s2 p1 (unchanged) ============
__global__ __launch_bounds__(256) void conv2_partial_kernel(
    const float* __restrict__ y1, const float* __restrict__ w,
    float* __restrict__ part)
{
    __shared__ float tin[4][33][36];
    __shared__ float twt[4][9][8];

    int bid = blockIdx.x;
    int ocg = bid & 3;
    int b   = (bid >> 2) & 7;
    int isp = bid >> 5;

    int tid = threadIdx.x;
    int ow  = tid & 15;
    int oh  = tid >> 4;

    const float* inb = y1 + (size_t)(b * 64 + isp * 4) * 1024;

    for (int lin = tid; lin < 4 * 33 * 34; lin += 256) {
        int c   = lin % 34;
        int t2  = lin / 34;
        int rr  = t2 % 33;
        int icc = t2 / 33;
        int ih  = rr - 1;
        int iw  = c - 1;
        float v = 0.f;
        if ((unsigned)ih < 32u && (unsigned)iw < 32u)
            v = inb[(icc * 32 + ih) * 32 + iw];
        tin[icc][rr][c] = v;
    }
    for (int i = tid; i < 288; i += 256) {
        int j   = i & 7;
        int k   = (i >> 3) % 9;
        int icc = i / 72;
        twt[icc][k][j] = w[(ocg * 8 + j) * 576 + (isp * 4 + icc) * 9 + k];
    }
    __syncthreads();

    double acc[8];
    #pragma unroll
    for (int j = 0; j < 8; ++j) acc[j] = 0.0;

    for (int icc = 0; icc < 4; ++icc) {
        double xv[9];
        #pragma unroll
        for (int kh = 0; kh < 3; ++kh)
            #pragma unroll
            for (int kw = 0; kw < 3; ++kw)
                xv[kh * 3 + kw] = (double)tin[icc][2 * oh + kh][2 * ow + kw];
        #pragma unroll
        for (int k = 0; k < 9; ++k) {
            float4 wa = *(const float4*)&twt[icc][k][0];
            float4 wb = *(const float4*)&twt[icc][k][4];
            acc[0] = fma(xv[k], (double)wa.x, acc[0]);
            acc[1] = fma(xv[k], (double)wa.y, acc[1]);
            acc[2] = fma(xv[k], (double)wa.z, acc[2]);
            acc[3] = fma(xv[k], (double)wa.w, acc[3]);
            acc[4] = fma(xv[k], (double)wb.x, acc[4]);
            acc[5] = fma(xv[k], (double)wb.y, acc[5]);
            acc[6] = fma(xv[k], (double)wb.z, acc[6]);
            acc[7] = fma(xv[k], (double)wb.w, acc[7]);
        }
    }
    int obase = ((b * 32 + ocg * 8) * 16 + oh) * 16 + ow;
    #pragma unroll
    for (int j = 0; j < 8; ++j)
        part[isp * 65536 + obase + j * 256] = (float)acc[j];
}

// ============ conv2 combine (unchanged) ============
__global__ __launch_bounds__(256) void conv2_combine_kernel(
    const float* __restrict__ part,
    const float* __restrict__ g, const float* __restrict__ be,
    const float* __restrict__ mn, const float* __restrict__ vr,
    float* __restrict__ y2)
{
    int idx = blockIdx.x * 256 + threadIdx.x;
    int oc = (idx >> 8) & 31;
    double s = 0.0;
    #pragma unroll
    for (int p = 0; p < 16; ++p) s += (double)part[idx + p * 65536];
    double inv = (double)g[oc] / sqrt((double)vr[oc] + BN_EPS);
    double o = s * inv + ((double)be[oc] - (double)mn[oc] * inv);
    y2[idx] = fmaxf((float)o, 0.f);
}

// ============ ybar (unchanged) ============
__global__ __launch_bounds__(256) void ybar_kernel(const float* __restrict__ y, double* __restrict__ ybar)
{
    __shared__ double s[4];
    int j = blockIdx.x;
    double v = (double)y[j * 256 + threadIdx.x];
    #pragma unroll
    for (int o = 32; o > 0; o >>= 1) v += __shfl_down(v, o, 64);
    if ((threadIdx.x & 63) == 0) s[threadIdx.x >> 6] = v;
    __syncthreads();
    if (threadIdx.x == 0) ybar[j] = (s[0] + s[1] + s[2] + s[3]) * (1.0 / 256.0);
}

// ============ centers (unchanged) ============
__global__ __launch_bounds__(64) void centers_kernel(
    const double* __restrict__ ybar, const float* __restrict__ w3,
    const float* __restrict__ g, const float* __restrict__ be,
    const float* __restrict__ mn, const float* __restrict__ vr,
    double* __restrict__ cen_ws, float* __restrict__ cen_out)
{
    int t = threadIdx.x;
    if (t < 48) {
        int b = t / 6;
        int k = t % 6;
        double acc = 0.0;
        for (int ic = 0; ic < 32; ++ic) acc = fma((double)w3[k * 32 + ic], ybar[b * 32 + ic], acc);
        double inv = (double)g[k] / sqrt((double)vr[k] + BN_EPS);
        double c = acc * inv + ((double)be[k] - (double)mn[k] * inv);
        cen_ws[t]  = c;
        cen_out[t] = (float)c;
    }
}

// ============ quantization (unchanged) ============
__global__ __launch_bounds__(256) void quant_kernel(
    const float* __restrict__ x, const double* __restrict__ centers,
    float* __restrict__ qbar, float* __restrict__ qsoft,
    float* __restrict__ qhard, float* __restrict__ sym)
{
    int vid = blockIdx.x * 256 + threadIdx.x;
    int b = vid >> 17;

    double c[6];
    float cf[6];
    #pragma unroll
    for (int k = 0; k < 6; ++k) { c[k] = centers[b * 6 + k]; cf[k] = (float)c[k]; }

    float4 xv = ((const float4*)x)[vid];
    float xs[4] = {xv.x, xv.y, xv.z, xv.w};
    float r_bar[4], r_soft[4], r_hard[4], r_sym[4];

    #pragma unroll
    for (int i = 0; i < 4; ++i) {
        double xx = (double)xs[i];
        double d[6];
        double dmin = 1e300;
        int amin = 0;
        #pragma unroll
        for (int k = 0; k < 6; ++k) {
            double t = xx - c[k];
            d[k] = t * t;
            if (d[k] < dmin) { dmin = d[k]; amin = k; }
        }
        float se = 0.f, sw = 0.f;
        #pragma unroll
        for (int k = 0; k < 6; ++k) {
            float e = __expf(SIGMA * (float)(dmin - d[k]));
            se += e;
            sw += e * cf[k];
        }
        float qs = sw / se;
        float qh = cf[amin];
        r_soft[i] = qs;
        r_hard[i] = qh;
        r_bar[i]  = qh;
        r_sym[i]  = (float)amin;
    }

    ((float4*)qbar)[vid]  = make_float4(r_bar[0],  r_bar[1],  r_bar[2],  r_bar[3]);
    ((float4*)qsoft)[vid] = make_float4(r_soft[0], r_soft[1], r_soft[2], r_soft[3]);
    ((float4*)qhard)[vid] = make_float4(r_hard[0], r_hard[1], r_hard[2], r_hard[3]);
    ((float4*)sym)[vid]   = make_float4(r_sym[0],  r_sym[1],  r_sym[2],  r_sym[3]);
}

extern "C" void kernel_launch(void* const* d_in, const int* in_sizes, int n_in,
                              void* d_out, int out_size, void* d_ws, size_t ws_size,
                              hipStream_t stream) {
    const float* x  = (const float*)d_in[0];
    const float* cf = (const float*)d_in[1];
    const float* w1 = (const float*)d_in[2];
    const float* g1 = (const float*)d_in[3];
    const float* b1 = (const float*)d_in[4];
    const float* m1 = (const float*)d_in[5];
    const float* v1 = (const float*)d_in[6];
    const float* w2 = (const float*)d_in[7];
    const float* g2 = (const float*)d_in[8];
    const float* b2 = (const float*)d_in[9];
    const float* m2 = (const float*)d_in[10];
    const float* v2 = (const float*)d_in[11];
    const float* w3 = (const float*)d_in[12];
    const float* g3 = (const float*)d_in[13];
    const float* b3 = (const float*)d_in[14];
    const float* m3 = (const float*)d_in[15];
    const float* v3 = (const float*)d_in[16];

    const int NELEM = 8 * 128 * 64 * 64;      // 4,194,304
    float* out   = (float*)d_out;
    float* qbar  = out;
    float* qsoft = out + (size_t)NELEM;
    float* qhard = out + (size_t)2 * NELEM;
    float* sym   = out + (size_t)3 * NELEM;
    float* cen_o = out + (size_t)4 * NELEM;

    char* ws = (char*)d_ws;
    float*  part1 = (float*)(ws);                        // 4 x 524288 f32 = 8 MB
    float*  y1    = (float*)(ws + 8388608);              // 524288 f32 = 2 MB
    float*  part2 = (float*)(ws + 10485760);             // 16 x 65536 f32 = 4 MB
    float*  y2    = (float*)(ws + 14680064);             // 65536 f32 = 256 KB
    double* yb    = (double*)(ws + 14942208);            // 256 f64
    double* cen   = (double*)(ws + 14944256);            // 48 f64
    double* w1d   = (double*)(ws + 14944640);            // 73728 f64 = 576 KB  (total ~14.8 MB)

    wcvt_kernel<<<288, 256, 0, stream>>>(w1, w1d);
    conv1_partial_kernel<<<512, 256, 0, stream>>>(cf, w1d, part1);
    conv1_combine_kernel<<<2048, 256, 0, stream>>>(part1, g1, b1, m1, v1, y1);
    conv2_partial_kernel<<<512, 256, 0, stream>>>(y1, w2, part2);
    conv2_combine_kernel<<<256, 256, 0, stream>>>(part2, g2, b2, m2, v2, y2);
    ybar_kernel<<<256, 256, 0, stream>>>(y2, yb);
    centers_kernel<<<1, 64, 0, stream>>>(yb, w3, g3, b3, m3, v3, cen, cen_o);
    quant_kernel<<<NELEM / 4 / 256, 256, 0, stream>>>(x, cen, qbar, qsoft, qhard, sym);
}